// Round 5
// baseline (427.334 us; speedup 1.0000x reference)
//
#include <hip/hip_runtime.h>

// B=4,S=2048,H=16,D=64. scores/8, mask->1e-20(~0), softmax, PV.
// Round 5 (fused): each wave ballot-compresses its own 64 mask rows
// (lane-contiguous NT i32x4 stream, 32:1) into a 16KB LDS bit-table, then runs
// the flash loop reading mask bits from LDS. No mask global traffic in the hot
// loop, no bitmask round-trip, phase1/phase2 overlap across the 2 blocks/CU.
// Masked positions -> exp2(0)=1, matching ref's 1e-20 pre-softmax semantics.

typedef __attribute__((ext_vector_type(8))) short short8;
typedef __attribute__((ext_vector_type(4))) float f32x4;
typedef __attribute__((ext_vector_type(4))) int   i32x4;
typedef unsigned int       u32;
typedef unsigned long long u64;

#define MFMA(a, b, c) __builtin_amdgcn_mfma_f32_16x16x32_bf16((a), (b), (c), 0, 0, 0)

static __device__ __forceinline__ short f2bf(float f) {
    __bf16 h = (__bf16)f;
    return __builtin_bit_cast(short, h);
}

constexpr int S_ = 2048, HD_ = 1024, STEPS_ = 32;
constexpr long KP_ELEMS = 64L * 32 * 4 * 2 * 64 * 8;   // 8,388,608 bf16 per tensor

// ---- prepack: thread t packs K-fragment t and V-fragment t (same as rounds 2-4).
__global__ __launch_bounds__(256) void prepack_kv(const float* __restrict__ K,
                                                  const float* __restrict__ V,
                                                  short* __restrict__ Kp,
                                                  short* __restrict__ Vp) {
    int t = blockIdx.x * 256 + threadIdx.x;
    int lane = t & 63, hf = (t >> 6) & 1, kt = (t >> 7) & 3, step = (t >> 9) & 31, bh = t >> 14;
    int g = lane >> 4, c = lane & 15, b = bh >> 4, h = bh & 15;

    {   // K: lane holds K[b, step*64+kt*16+c, h, hf*32+g*8 .. +7]
        int row = step * 64 + kt * 16 + c;
        const float* src = K + (long)(b * S_ + row) * HD_ + h * 64 + hf * 32 + g * 8;
        f32x4 x0 = *(const f32x4*)src, x1 = *(const f32x4*)(src + 4);
        short8 o;
        o[0] = f2bf(x0[0]); o[1] = f2bf(x0[1]); o[2] = f2bf(x0[2]); o[3] = f2bf(x0[3]);
        o[4] = f2bf(x1[0]); o[5] = f2bf(x1[1]); o[6] = f2bf(x1[2]); o[7] = f2bf(x1[3]);
        *(short8*)(Kp + (long)t * 8) = o;
    }
    {   // V (kt plays dt): kappa-ordered V^T fragment
        int col = kt * 16 + c, row0 = step * 64 + hf * 32;
        const float* vb = V + (long)(b * S_) * HD_ + h * 64 + col;
        short8 o;
#pragma unroll
        for (int i = 0; i < 8; ++i) {
            int row = row0 + ((i < 4) ? g * 4 + i : 16 + g * 4 + (i - 4));
            o[i] = f2bf(vb[(long)row * HD_]);
        }
        *(short8*)(Vp + (long)t * 8) = o;
    }
}

// ---- fused attention: 512 blocks x 256 thr; wave owns 64 q-rows.
// LDS bit-table layout (per wave, u64 units, base wave*2048):
//   idx(row, chunk, r) = row*32 + ((chunk ^ (row&7)) << 2) + r
//   where row=0..63 (local q-row), chunk=0..7 (256-kv chunk), r=0..3.
//   Bit l of entry (row,chunk,r) = mask(q=q0+row, kv=chunk*256 + l*4 + r).
__global__ __launch_bounds__(256, 2)
void attn_fused(const float* __restrict__ Q, const short* __restrict__ Kp,
                const short* __restrict__ Vp, const int* __restrict__ M,
                float* __restrict__ O)
{
    const float QSCALE = 0.125f * 1.44269504088896340736f;  // 1/sqrt(64) * log2(e)

    __shared__ u64 smem[8192];   // 64 KiB

    // XCD swizzle: XCD i gets bh 8i..8i+7; all 8 q-blocks of a head co-resident
    int orig = blockIdx.x;
    int wg   = (orig & 7) * 64 + (orig >> 3);
    int bh   = wg >> 3, qb = wg & 7;
    int b    = bh >> 4, h = bh & 15;

    int lane = threadIdx.x & 63, wave = threadIdx.x >> 6;
    int g = lane >> 4, c = lane & 15;
    int q0 = qb * 256 + wave * 64;

    u64* swv = smem + wave * 2048;

    const float* qbase = Q + (long)(b * S_) * HD_ + h * 64;
    const int*   mbase = M + ((long)bh << 22);
    float*       obase = O + (long)(b * S_) * HD_ + h * 64;
    const short* kpb   = Kp + (long)bh * STEPS_ * 4096;
    const short* vpb   = Vp + (long)bh * STEPS_ * 4096;

    // Q fragments (B-operand): lane holds Q[q0+qt*16+c][hf*32+g*8 ..+7] * QSCALE
    short8 qf[4][2];
#pragma unroll
    for (int qt = 0; qt < 4; ++qt) {
        const float* qr = qbase + (long)(q0 + qt * 16 + c) * HD_;
#pragma unroll
        for (int hf = 0; hf < 2; ++hf) {
            f32x4 x0 = *(const f32x4*)(qr + hf * 32 + g * 8);
            f32x4 x1 = *(const f32x4*)(qr + hf * 32 + g * 8 + 4);
            short8 t;
            t[0] = f2bf(x0[0] * QSCALE); t[1] = f2bf(x0[1] * QSCALE);
            t[2] = f2bf(x0[2] * QSCALE); t[3] = f2bf(x0[3] * QSCALE);
            t[4] = f2bf(x1[0] * QSCALE); t[5] = f2bf(x1[1] * QSCALE);
            t[6] = f2bf(x1[2] * QSCALE); t[7] = f2bf(x1[3] * QSCALE);
            qf[qt][hf] = t;
        }
    }

    // ---- phase 1: ballot-compress my wave's 64 mask rows into LDS bits.
    // Wave load = 1 KiB lane-contiguous (lane reads i32x4 at lane*16B). NT so the
    // one-shot stream doesn't evict Kp/Vp from L2.
    {
        const int* mr = mbase + (long)q0 * 2048;
#pragma unroll 2
        for (int row = 0; row < 64; ++row) {
            const int* rp = mr + (long)row * 2048 + lane * 4;
#pragma unroll
            for (int chunk = 0; chunk < 8; ++chunk) {
                i32x4 m = __builtin_nontemporal_load((const i32x4*)(rp + chunk * 256));
                u64 b0 = __ballot(m[0] != 0);
                u64 b1 = __ballot(m[1] != 0);
                u64 b2 = __ballot(m[2] != 0);
                u64 b3 = __ballot(m[3] != 0);
                u64 sel = b0;
                sel = (lane == 1) ? b1 : sel;
                sel = (lane == 2) ? b2 : sel;
                sel = (lane == 3) ? b3 : sel;
                if (lane < 4)
                    swv[row * 32 + ((chunk ^ (row & 7)) << 2) + lane] = sel;
            }
        }
    }
    // no barrier: each wave reads only its own LDS region (lgkmcnt orders it)

    f32x4 acc[4][4];
#pragma unroll
    for (int qt = 0; qt < 4; ++qt)
#pragma unroll
        for (int dt = 0; dt < 4; ++dt) acc[qt][dt] = (f32x4){0.f, 0.f, 0.f, 0.f};
    float lsum[4] = {0.f, 0.f, 0.f, 0.f};

#pragma unroll 1
    for (int step = 0; step < STEPS_; ++step) {
        const short* kp = kpb + (long)step * 4096;
        const short* vp = vpb + (long)step * 4096;
        short8 kf[4][2], vf[4][2];
#pragma unroll
        for (int kt = 0; kt < 4; ++kt)
#pragma unroll
            for (int hf = 0; hf < 2; ++hf) {
                kf[kt][hf] = *(const short8*)(kp + ((kt * 2 + hf) * 64 + lane) * 8);
                vf[kt][hf] = *(const short8*)(vp + ((kt * 2 + hf) * 64 + lane) * 8);
            }

        int chunk = step >> 2;
        int sub16 = (step & 3) << 4;

#pragma unroll
        for (int qt = 0; qt < 4; ++qt) {
            f32x4 st[4];
#pragma unroll
            for (int kt = 0; kt < 4; ++kt) {
                f32x4 z = (f32x4){0.f, 0.f, 0.f, 0.f};
                z = MFMA(kf[kt][0], qf[qt][0], z);
                z = MFMA(kf[kt][1], qf[qt][1], z);
                st[kt] = z;   // kv = step*64+kt*16+g*4+r, q = q0+qt*16+c (log2e-scaled)
            }

            // mask bits from LDS: 32B per (qt, 4-step group)
            int lr = qt * 16 + c;
            const u64* bp = &swv[lr * 32 + ((chunk ^ (lr & 7)) << 2)];
            u64 B0 = bp[0], B1 = bp[1], B2 = bp[2], B3 = bp[3];
            u32 fld[4];
            fld[0] = (u32)(B0 >> sub16) & 0xffffu;
            fld[1] = (u32)(B1 >> sub16) & 0xffffu;
            fld[2] = (u32)(B2 >> sub16) & 0xffffu;
            fld[3] = (u32)(B3 >> sub16) & 0xffffu;

            float p[4][4];
            float s = 0.f;
#pragma unroll
            for (int kt = 0; kt < 4; ++kt) {
#pragma unroll
                for (int r = 0; r < 4; ++r) {
                    u32 bit = (fld[r] >> (kt * 4 + g)) & 1u;
                    float val = bit ? st[kt][r] : 0.0f;   // masked -> exp2(0)=1
                    float e = exp2f(val);
                    p[kt][r] = e;
                    s += e;
                }
            }
            lsum[qt] += s;

            short8 pb0, pb1;
            pb0[0] = f2bf(p[0][0]); pb0[1] = f2bf(p[0][1]); pb0[2] = f2bf(p[0][2]); pb0[3] = f2bf(p[0][3]);
            pb0[4] = f2bf(p[1][0]); pb0[5] = f2bf(p[1][1]); pb0[6] = f2bf(p[1][2]); pb0[7] = f2bf(p[1][3]);
            pb1[0] = f2bf(p[2][0]); pb1[1] = f2bf(p[2][1]); pb1[2] = f2bf(p[2][2]); pb1[3] = f2bf(p[2][3]);
            pb1[4] = f2bf(p[3][0]); pb1[5] = f2bf(p[3][1]); pb1[6] = f2bf(p[3][2]); pb1[7] = f2bf(p[3][3]);

#pragma unroll
            for (int dt = 0; dt < 4; ++dt) {
                acc[qt][dt] = MFMA(vf[dt][0], pb0, acc[qt][dt]);
                acc[qt][dt] = MFMA(vf[dt][1], pb1, acc[qt][dt]);
            }
        }
    }

    // epilogue: reduce row sums across g-groups, normalize, store
#pragma unroll
    for (int qt = 0; qt < 4; ++qt) {
        float t0 = lsum[qt];
        t0 += __shfl_xor(t0, 16);
        t0 += __shfl_xor(t0, 32);
        float inv = 1.0f / t0;
        float* orow = obase + (long)(q0 + qt * 16 + c) * HD_;
#pragma unroll
        for (int dt = 0; dt < 4; ++dt) {
            f32x4 o = acc[qt][dt] * inv;
            __builtin_nontemporal_store(o, (f32x4*)(orow + dt * 16 + g * 4));
        }
    }
}

// ---- fallback (only if ws too small): round-1 style fused kernel ----
__global__ __launch_bounds__(256, 2)
void attn_fwd(const float* __restrict__ Q, const float* __restrict__ K,
              const float* __restrict__ V, const int* __restrict__ M,
              float* __restrict__ O)
{
    const float QSCALE = 0.125f * 1.44269504088896340736f;
    int orig = blockIdx.x;
    int wg   = (orig & 7) * 64 + (orig >> 3);
    int bh   = wg >> 3, qb = wg & 7;
    int b    = bh >> 4, h = bh & 15;
    int lane = threadIdx.x & 63, wave = threadIdx.x >> 6;
    int g = lane >> 4, c = lane & 15;
    int q0 = qb * 256 + wave * 64;

    const float* qbase = Q + (long)(b * S_) * HD_ + h * 64;
    const float* kbase = K + (long)(b * S_) * HD_ + h * 64;
    const float* vbase = V + (long)(b * S_) * HD_ + h * 64;
    const int*   mbase = M + ((long)bh << 22);
    float*       obase = O + (long)(b * S_) * HD_ + h * 64;

    short8 qf[4][2];
#pragma unroll
    for (int qt = 0; qt < 4; ++qt) {
        const float* qr = qbase + (long)(q0 + qt * 16 + c) * HD_;
#pragma unroll
        for (int hf = 0; hf < 2; ++hf) {
            f32x4 x0 = *(const f32x4*)(qr + hf * 32 + g * 8);
            f32x4 x1 = *(const f32x4*)(qr + hf * 32 + g * 8 + 4);
            short8 t;
            t[0] = f2bf(x0[0] * QSCALE); t[1] = f2bf(x0[1] * QSCALE);
            t[2] = f2bf(x0[2] * QSCALE); t[3] = f2bf(x0[3] * QSCALE);
            t[4] = f2bf(x1[0] * QSCALE); t[5] = f2bf(x1[1] * QSCALE);
            t[6] = f2bf(x1[2] * QSCALE); t[7] = f2bf(x1[3] * QSCALE);
            qf[qt][hf] = t;
        }
    }

    f32x4 acc[4][4];
#pragma unroll
    for (int qt = 0; qt < 4; ++qt)
#pragma unroll
        for (int dt = 0; dt < 4; ++dt) acc[qt][dt] = (f32x4){0.f, 0.f, 0.f, 0.f};
    float lsum[4] = {0.f, 0.f, 0.f, 0.f};

#pragma unroll 1
    for (int step = 0; step < STEPS_; ++step) {
        int kv0 = step * 64;
        short8 kf[4][2];
#pragma unroll
        for (int kt = 0; kt < 4; ++kt) {
            const float* kr = kbase + (long)(kv0 + kt * 16 + c) * HD_;
#pragma unroll
            for (int hf = 0; hf < 2; ++hf) {
                f32x4 x0 = *(const f32x4*)(kr + hf * 32 + g * 8);
                f32x4 x1 = *(const f32x4*)(kr + hf * 32 + g * 8 + 4);
                short8 t;
                t[0] = f2bf(x0[0]); t[1] = f2bf(x0[1]); t[2] = f2bf(x0[2]); t[3] = f2bf(x0[3]);
                t[4] = f2bf(x1[0]); t[5] = f2bf(x1[1]); t[6] = f2bf(x1[2]); t[7] = f2bf(x1[3]);
                kf[kt][hf] = t;
            }
        }
        short8 vf[4][2];
#pragma unroll
        for (int hf = 0; hf < 2; ++hf) {
            const float* vr[8];
#pragma unroll
            for (int i = 0; i < 4; ++i) {
                vr[i]     = vbase + (long)(kv0 + hf * 32 + g * 4 + i) * HD_ + c;
                vr[4 + i] = vbase + (long)(kv0 + hf * 32 + 16 + g * 4 + i) * HD_ + c;
            }
#pragma unroll
            for (int dt = 0; dt < 4; ++dt) {
                short8 t;
#pragma unroll
                for (int i = 0; i < 8; ++i) t[i] = f2bf(vr[i][dt * 16]);
                vf[dt][hf] = t;
            }
        }
#pragma unroll
        for (int qt = 0; qt < 4; ++qt) {
            f32x4 st[4];
#pragma unroll
            for (int kt = 0; kt < 4; ++kt) {
                f32x4 z = (f32x4){0.f, 0.f, 0.f, 0.f};
                z = MFMA(kf[kt][0], qf[qt][0], z);
                z = MFMA(kf[kt][1], qf[qt][1], z);
                st[kt] = z;
            }
            const int* mrp = mbase + ((long)(q0 + qt * 16 + c) << 11) + kv0 + g * 4;
            float p[4][4];
            float s = 0.f;
#pragma unroll
            for (int kt = 0; kt < 4; ++kt) {
                i32x4 mkv = *(const i32x4*)(mrp + kt * 16);
#pragma unroll
                for (int r = 0; r < 4; ++r) {
                    float val = (mkv[r] != 0) ? st[kt][r] : 0.0f;
                    float e = exp2f(val);
                    p[kt][r] = e;
                    s += e;
                }
            }
            lsum[qt] += s;
            short8 pb0, pb1;
            pb0[0] = f2bf(p[0][0]); pb0[1] = f2bf(p[0][1]); pb0[2] = f2bf(p[0][2]); pb0[3] = f2bf(p[0][3]);
            pb0[4] = f2bf(p[1][0]); pb0[5] = f2bf(p[1][1]); pb0[6] = f2bf(p[1][2]); pb0[7] = f2bf(p[1][3]);
            pb1[0] = f2bf(p[2][0]); pb1[1] = f2bf(p[2][1]); pb1[2] = f2bf(p[2][2]); pb1[3] = f2bf(p[2][3]);
            pb1[4] = f2bf(p[3][0]); pb1[5] = f2bf(p[3][1]); pb1[6] = f2bf(p[3][2]); pb1[7] = f2bf(p[3][3]);
#pragma unroll
            for (int dt = 0; dt < 4; ++dt) {
                acc[qt][dt] = MFMA(vf[dt][0], pb0, acc[qt][dt]);
                acc[qt][dt] = MFMA(vf[dt][1], pb1, acc[qt][dt]);
            }
        }
    }
#pragma unroll
    for (int qt = 0; qt < 4; ++qt) {
        float t0 = lsum[qt];
        t0 += __shfl_xor(t0, 16);
        t0 += __shfl_xor(t0, 32);
        float inv = 1.0f / t0;
        float* orow = obase + (long)(q0 + qt * 16 + c) * HD_;
#pragma unroll
        for (int dt = 0; dt < 4; ++dt) {
            f32x4 o = acc[qt][dt] * inv;
            *(f32x4*)(orow + dt * 16 + g * 4) = o;
        }
    }
}

extern "C" void kernel_launch(void* const* d_in, const int* in_sizes, int n_in,
                              void* d_out, int out_size, void* d_ws, size_t ws_size,
                              hipStream_t stream) {
    const float* q = (const float*)d_in[0];
    const float* k = (const float*)d_in[1];
    const float* v = (const float*)d_in[2];
    const int*   m = (const int*)d_in[3];
    float* out = (float*)d_out;

    size_t need = (size_t)2 * KP_ELEMS * sizeof(short);   // 32 MiB
    if (ws_size >= need) {
        short* Kp = (short*)d_ws;
        short* Vp = Kp + KP_ELEMS;
        prepack_kv<<<dim3(4096), dim3(256), 0, stream>>>(k, v, Kp, Vp);
        attn_fused<<<dim3(512), dim3(256), 0, stream>>>(q, Kp, Vp, m, out);
    } else {
        attn_fwd<<<dim3(512), dim3(256), 0, stream>>>(q, k, v, m, out);
    }
}

// Round 6
// 299.750 us; speedup vs baseline: 1.4256x; 1.4256x over previous
//
#include <hip/hip_runtime.h>

// B=4,S=2048,H=16,D=64. scores/8, mask->1e-20(~0), softmax, PV.
// Round 6: fused kernel, ballot-FREE wave-local mask compression.
// Phase A: each wave streams its own 64 mask rows (lane-contiguous NT i32x4,
// 1KiB/wave-load, ~16KiB/wave in flight) and packs 32:1 into per-lane u32 bits
// -> 16KB LDS table per wave (64KB/block). No cross-lane ops, no barriers.
// Phase B: round-2 flash loop; mask bits via 4x ds_read_b32 per (step,qt).
// Masked positions -> exp2(0)=1, matching ref's 1e-20 pre-softmax semantics.

typedef __attribute__((ext_vector_type(8))) short short8;
typedef __attribute__((ext_vector_type(4))) float f32x4;
typedef __attribute__((ext_vector_type(4))) int   i32x4;
typedef unsigned int       u32;
typedef unsigned long long u64;

#define MFMA(a, b, c) __builtin_amdgcn_mfma_f32_16x16x32_bf16((a), (b), (c), 0, 0, 0)

static __device__ __forceinline__ short f2bf(float f) {
    __bf16 h = (__bf16)f;
    return __builtin_bit_cast(short, h);
}

constexpr int S_ = 2048, HD_ = 1024, STEPS_ = 32;
constexpr long KP_ELEMS = 64L * 32 * 4 * 2 * 64 * 8;   // 8,388,608 bf16 per tensor

// ---- prepack: thread t packs K-fragment t and V-fragment t (same as rounds 2-5).
__global__ __launch_bounds__(256) void prepack_kv(const float* __restrict__ K,
                                                  const float* __restrict__ V,
                                                  short* __restrict__ Kp,
                                                  short* __restrict__ Vp) {
    int t = blockIdx.x * 256 + threadIdx.x;
    int lane = t & 63, hf = (t >> 6) & 1, kt = (t >> 7) & 3, step = (t >> 9) & 31, bh = t >> 14;
    int g = lane >> 4, c = lane & 15, b = bh >> 4, h = bh & 15;

    {   // K: lane holds K[b, step*64+kt*16+c, h, hf*32+g*8 .. +7]
        int row = step * 64 + kt * 16 + c;
        const float* src = K + (long)(b * S_ + row) * HD_ + h * 64 + hf * 32 + g * 8;
        f32x4 x0 = *(const f32x4*)src, x1 = *(const f32x4*)(src + 4);
        short8 o;
        o[0] = f2bf(x0[0]); o[1] = f2bf(x0[1]); o[2] = f2bf(x0[2]); o[3] = f2bf(x0[3]);
        o[4] = f2bf(x1[0]); o[5] = f2bf(x1[1]); o[6] = f2bf(x1[2]); o[7] = f2bf(x1[3]);
        *(short8*)(Kp + (long)t * 8) = o;
    }
    {   // V (kt plays dt): kappa-ordered V^T fragment
        int col = kt * 16 + c, row0 = step * 64 + hf * 32;
        const float* vb = V + (long)(b * S_) * HD_ + h * 64 + col;
        short8 o;
#pragma unroll
        for (int i = 0; i < 8; ++i) {
            int row = row0 + ((i < 4) ? g * 4 + i : 16 + g * 4 + (i - 4));
            o[i] = f2bf(vb[(long)row * HD_]);
        }
        *(short8*)(Vp + (long)t * 8) = o;
    }
}

// ---- fused attention: 512 blocks x 256 thr; wave owns 64 q-rows.
// LDS bit-table (per wave, u32 units, 16KB): entry(row, w) at
//   idx = row*64 + ((w + 4*row) & 63), bit (j*4+i) = mask(q0+row, j*256 + w*4 + i).
__global__ __launch_bounds__(256, 2)
void attn_fused2(const float* __restrict__ Q, const short* __restrict__ Kp,
                 const short* __restrict__ Vp, const int* __restrict__ M,
                 float* __restrict__ O)
{
    const float QSCALE = 0.125f * 1.44269504088896340736f;  // 1/sqrt(64) * log2(e)

    __shared__ u32 sbits[16384];   // 64 KiB (4 waves x 16 KB)

    // XCD swizzle: XCD i gets bh 8i..8i+7; all 8 q-blocks of a head co-resident
    int orig = blockIdx.x;
    int wg   = (orig & 7) * 64 + (orig >> 3);
    int bh   = wg >> 3, qb = wg & 7;
    int b    = bh >> 4, h = bh & 15;

    int lane = threadIdx.x & 63, wave = threadIdx.x >> 6;
    int g = lane >> 4, c = lane & 15;
    int q0 = qb * 256 + wave * 64;

    u32* sw = sbits + wave * 4096;

    const float* qbase = Q + (long)(b * S_) * HD_ + h * 64;
    const int*   mbase = M + ((long)bh << 22);
    float*       obase = O + (long)(b * S_) * HD_ + h * 64;
    const short* kpb   = Kp + (long)bh * STEPS_ * 4096;
    const short* vpb   = Vp + (long)bh * STEPS_ * 4096;

    // Q fragments (B-operand): lane holds Q[q0+qt*16+c][hf*32+g*8 ..+7] * QSCALE
    short8 qf[4][2];
#pragma unroll
    for (int qt = 0; qt < 4; ++qt) {
        const float* qr = qbase + (long)(q0 + qt * 16 + c) * HD_;
#pragma unroll
        for (int hf = 0; hf < 2; ++hf) {
            f32x4 x0 = *(const f32x4*)(qr + hf * 32 + g * 8);
            f32x4 x1 = *(const f32x4*)(qr + hf * 32 + g * 8 + 4);
            short8 t;
            t[0] = f2bf(x0[0] * QSCALE); t[1] = f2bf(x0[1] * QSCALE);
            t[2] = f2bf(x0[2] * QSCALE); t[3] = f2bf(x0[3] * QSCALE);
            t[4] = f2bf(x1[0] * QSCALE); t[5] = f2bf(x1[1] * QSCALE);
            t[6] = f2bf(x1[2] * QSCALE); t[7] = f2bf(x1[3] * QSCALE);
            qf[qt][hf] = t;
        }
    }

    // ---- phase A: compress my wave's 64 mask rows into LDS (ballot-free).
    // Per row: 8 lane-contiguous NT i32x4 loads (1 KiB each), per-lane bit pack,
    // one ds_write_b32. No cross-lane dependency -> deep load pipelining.
    {
        const int* mr = mbase + ((long)q0 << 11) + lane * 4;
#pragma unroll 2
        for (int row = 0; row < 64; ++row) {
            const int* rp = mr + ((long)row << 11);
            u32 w = 0;
#pragma unroll
            for (int j = 0; j < 8; ++j) {
                i32x4 m = __builtin_nontemporal_load((const i32x4*)(rp + j * 256));
                w |= (m[0] != 0 ? 1u : 0u) << (j * 4);
                w |= (m[1] != 0 ? 1u : 0u) << (j * 4 + 1);
                w |= (m[2] != 0 ? 1u : 0u) << (j * 4 + 2);
                w |= (m[3] != 0 ? 1u : 0u) << (j * 4 + 3);
            }
            sw[row * 64 + ((lane + row * 4) & 63)] = w;
        }
    }
    // no barrier: each wave reads only its own LDS region (lgkmcnt orders it)

    f32x4 acc[4][4];
#pragma unroll
    for (int qt = 0; qt < 4; ++qt)
#pragma unroll
        for (int dt = 0; dt < 4; ++dt) acc[qt][dt] = (f32x4){0.f, 0.f, 0.f, 0.f};
    float lsum[4] = {0.f, 0.f, 0.f, 0.f};

#pragma unroll 1
    for (int step = 0; step < STEPS_; ++step) {
        const short* kp = kpb + (long)step * 4096;
        const short* vp = vpb + (long)step * 4096;
        short8 kf[4][2], vf[4][2];
#pragma unroll
        for (int kt = 0; kt < 4; ++kt)
#pragma unroll
            for (int hf = 0; hf < 2; ++hf) {
                kf[kt][hf] = *(const short8*)(kp + ((kt * 2 + hf) * 64 + lane) * 8);
                vf[kt][hf] = *(const short8*)(vp + ((kt * 2 + hf) * 64 + lane) * 8);
            }

        int wbase = (step & 3) * 16 + g;    // word index base for this step
        int shft  = (step >> 2) * 4;        // bit base within word

#pragma unroll
        for (int qt = 0; qt < 4; ++qt) {
            f32x4 st[4];
#pragma unroll
            for (int kt = 0; kt < 4; ++kt) {
                f32x4 z = (f32x4){0.f, 0.f, 0.f, 0.f};
                z = MFMA(kf[kt][0], qf[qt][0], z);
                z = MFMA(kf[kt][1], qf[qt][1], z);
                st[kt] = z;   // kv = step*64+kt*16+g*4+r, q = q0+qt*16+c (log2e-scaled)
            }

            // mask bits from LDS: 4x b32, swizzled
            int row = qt * 16 + c;
            u32 fld[4];
#pragma unroll
            for (int kt = 0; kt < 4; ++kt) {
                int w = wbase + kt * 4;
                fld[kt] = sw[row * 64 + ((w + row * 4) & 63)] >> shft;
            }

            float p[4][4];
            float s = 0.f;
#pragma unroll
            for (int kt = 0; kt < 4; ++kt) {
#pragma unroll
                for (int r = 0; r < 4; ++r) {
                    u32 bit = (fld[kt] >> r) & 1u;
                    float val = bit ? st[kt][r] : 0.0f;   // masked -> exp2(0)=1
                    float e = exp2f(val);
                    p[kt][r] = e;
                    s += e;
                }
            }
            lsum[qt] += s;

            short8 pb0, pb1;
            pb0[0] = f2bf(p[0][0]); pb0[1] = f2bf(p[0][1]); pb0[2] = f2bf(p[0][2]); pb0[3] = f2bf(p[0][3]);
            pb0[4] = f2bf(p[1][0]); pb0[5] = f2bf(p[1][1]); pb0[6] = f2bf(p[1][2]); pb0[7] = f2bf(p[1][3]);
            pb1[0] = f2bf(p[2][0]); pb1[1] = f2bf(p[2][1]); pb1[2] = f2bf(p[2][2]); pb1[3] = f2bf(p[2][3]);
            pb1[4] = f2bf(p[3][0]); pb1[5] = f2bf(p[3][1]); pb1[6] = f2bf(p[3][2]); pb1[7] = f2bf(p[3][3]);

#pragma unroll
            for (int dt = 0; dt < 4; ++dt) {
                acc[qt][dt] = MFMA(vf[dt][0], pb0, acc[qt][dt]);
                acc[qt][dt] = MFMA(vf[dt][1], pb1, acc[qt][dt]);
            }
        }
    }

    // epilogue: reduce row sums across g-groups, normalize, store
#pragma unroll
    for (int qt = 0; qt < 4; ++qt) {
        float t0 = lsum[qt];
        t0 += __shfl_xor(t0, 16);
        t0 += __shfl_xor(t0, 32);
        float inv = 1.0f / t0;
        float* orow = obase + (long)(q0 + qt * 16 + c) * HD_;
#pragma unroll
        for (int dt = 0; dt < 4; ++dt) {
            f32x4 o = acc[qt][dt] * inv;
            __builtin_nontemporal_store(o, (f32x4*)(orow + dt * 16 + g * 4));
        }
    }
}

// ---- fallback (only if ws too small): round-1 style fused kernel ----
__global__ __launch_bounds__(256, 2)
void attn_fwd(const float* __restrict__ Q, const float* __restrict__ K,
              const float* __restrict__ V, const int* __restrict__ M,
              float* __restrict__ O)
{
    const float QSCALE = 0.125f * 1.44269504088896340736f;
    int orig = blockIdx.x;
    int wg   = (orig & 7) * 64 + (orig >> 3);
    int bh   = wg >> 3, qb = wg & 7;
    int b    = bh >> 4, h = bh & 15;
    int lane = threadIdx.x & 63, wave = threadIdx.x >> 6;
    int g = lane >> 4, c = lane & 15;
    int q0 = qb * 256 + wave * 64;

    const float* qbase = Q + (long)(b * S_) * HD_ + h * 64;
    const float* kbase = K + (long)(b * S_) * HD_ + h * 64;
    const float* vbase = V + (long)(b * S_) * HD_ + h * 64;
    const int*   mbase = M + ((long)bh << 22);
    float*       obase = O + (long)(b * S_) * HD_ + h * 64;

    short8 qf[4][2];
#pragma unroll
    for (int qt = 0; qt < 4; ++qt) {
        const float* qr = qbase + (long)(q0 + qt * 16 + c) * HD_;
#pragma unroll
        for (int hf = 0; hf < 2; ++hf) {
            f32x4 x0 = *(const f32x4*)(qr + hf * 32 + g * 8);
            f32x4 x1 = *(const f32x4*)(qr + hf * 32 + g * 8 + 4);
            short8 t;
            t[0] = f2bf(x0[0] * QSCALE); t[1] = f2bf(x0[1] * QSCALE);
            t[2] = f2bf(x0[2] * QSCALE); t[3] = f2bf(x0[3] * QSCALE);
            t[4] = f2bf(x1[0] * QSCALE); t[5] = f2bf(x1[1] * QSCALE);
            t[6] = f2bf(x1[2] * QSCALE); t[7] = f2bf(x1[3] * QSCALE);
            qf[qt][hf] = t;
        }
    }

    f32x4 acc[4][4];
#pragma unroll
    for (int qt = 0; qt < 4; ++qt)
#pragma unroll
        for (int dt = 0; dt < 4; ++dt) acc[qt][dt] = (f32x4){0.f, 0.f, 0.f, 0.f};
    float lsum[4] = {0.f, 0.f, 0.f, 0.f};

#pragma unroll 1
    for (int step = 0; step < STEPS_; ++step) {
        int kv0 = step * 64;
        short8 kf[4][2];
#pragma unroll
        for (int kt = 0; kt < 4; ++kt) {
            const float* kr = kbase + (long)(kv0 + kt * 16 + c) * HD_;
#pragma unroll
            for (int hf = 0; hf < 2; ++hf) {
                f32x4 x0 = *(const f32x4*)(kr + hf * 32 + g * 8);
                f32x4 x1 = *(const f32x4*)(kr + hf * 32 + g * 8 + 4);
                short8 t;
                t[0] = f2bf(x0[0]); t[1] = f2bf(x0[1]); t[2] = f2bf(x0[2]); t[3] = f2bf(x0[3]);
                t[4] = f2bf(x1[0]); t[5] = f2bf(x1[1]); t[6] = f2bf(x1[2]); t[7] = f2bf(x1[3]);
                kf[kt][hf] = t;
            }
        }
        short8 vf[4][2];
#pragma unroll
        for (int hf = 0; hf < 2; ++hf) {
            const float* vr[8];
#pragma unroll
            for (int i = 0; i < 4; ++i) {
                vr[i]     = vbase + (long)(kv0 + hf * 32 + g * 4 + i) * HD_ + c;
                vr[4 + i] = vbase + (long)(kv0 + hf * 32 + 16 + g * 4 + i) * HD_ + c;
            }
#pragma unroll
            for (int dt = 0; dt < 4; ++dt) {
                short8 t;
#pragma unroll
                for (int i = 0; i < 8; ++i) t[i] = f2bf(vr[i][dt * 16]);
                vf[dt][hf] = t;
            }
        }
#pragma unroll
        for (int qt = 0; qt < 4; ++qt) {
            f32x4 st[4];
#pragma unroll
            for (int kt = 0; kt < 4; ++kt) {
                f32x4 z = (f32x4){0.f, 0.f, 0.f, 0.f};
                z = MFMA(kf[kt][0], qf[qt][0], z);
                z = MFMA(kf[kt][1], qf[qt][1], z);
                st[kt] = z;
            }
            const int* mrp = mbase + ((long)(q0 + qt * 16 + c) << 11) + kv0 + g * 4;
            float p[4][4];
            float s = 0.f;
#pragma unroll
            for (int kt = 0; kt < 4; ++kt) {
                i32x4 mkv = *(const i32x4*)(mrp + kt * 16);
#pragma unroll
                for (int r = 0; r < 4; ++r) {
                    float val = (mkv[r] != 0) ? st[kt][r] : 0.0f;
                    float e = exp2f(val);
                    p[kt][r] = e;
                    s += e;
                }
            }
            lsum[qt] += s;
            short8 pb0, pb1;
            pb0[0] = f2bf(p[0][0]); pb0[1] = f2bf(p[0][1]); pb0[2] = f2bf(p[0][2]); pb0[3] = f2bf(p[0][3]);
            pb0[4] = f2bf(p[1][0]); pb0[5] = f2bf(p[1][1]); pb0[6] = f2bf(p[1][2]); pb0[7] = f2bf(p[1][3]);
            pb1[0] = f2bf(p[2][0]); pb1[1] = f2bf(p[2][1]); pb1[2] = f2bf(p[2][2]); pb1[3] = f2bf(p[2][3]);
            pb1[4] = f2bf(p[3][0]); pb1[5] = f2bf(p[3][1]); pb1[6] = f2bf(p[3][2]); pb1[7] = f2bf(p[3][3]);
#pragma unroll
            for (int dt = 0; dt < 4; ++dt) {
                acc[qt][dt] = MFMA(vf[dt][0], pb0, acc[qt][dt]);
                acc[qt][dt] = MFMA(vf[dt][1], pb1, acc[qt][dt]);
            }
        }
    }
#pragma unroll
    for (int qt = 0; qt < 4; ++qt) {
        float t0 = lsum[qt];
        t0 += __shfl_xor(t0, 16);
        t0 += __shfl_xor(t0, 32);
        float inv = 1.0f / t0;
        float* orow = obase + (long)(q0 + qt * 16 + c) * HD_;
#pragma unroll
        for (int dt = 0; dt < 4; ++dt) {
            f32x4 o = acc[qt][dt] * inv;
            *(f32x4*)(orow + dt * 16 + g * 4) = o;
        }
    }
}

extern "C" void kernel_launch(void* const* d_in, const int* in_sizes, int n_in,
                              void* d_out, int out_size, void* d_ws, size_t ws_size,
                              hipStream_t stream) {
    const float* q = (const float*)d_in[0];
    const float* k = (const float*)d_in[1];
    const float* v = (const float*)d_in[2];
    const int*   m = (const int*)d_in[3];
    float* out = (float*)d_out;

    size_t need = (size_t)2 * KP_ELEMS * sizeof(short);   // 32 MiB
    if (ws_size >= need) {
        short* Kp = (short*)d_ws;
        short* Vp = Kp + KP_ELEMS;
        prepack_kv<<<dim3(4096), dim3(256), 0, stream>>>(k, v, Kp, Vp);
        attn_fused2<<<dim3(512), dim3(256), 0, stream>>>(q, Kp, Vp, m, out);
    } else {
        attn_fwd<<<dim3(512), dim3(256), 0, stream>>>(q, k, v, m, out);
    }
}